// Round 13
// baseline (104.664 us; speedup 1.0000x reference)
//
#include <hip/hip_runtime.h>
#include <hip/hip_bf16.h>

#define NFREQ 512
#define KDIM  1024   // combined k (m || p)
#define CDIM  1024   // NFFT output channels
#define TDIM  4096
#define BATCH 8
#define NT    16     // K-tiles of 64

// LDS: per buffer A 256x64 bf16 = 32 KB, B 128x64 bf16 = 16 KB
#define ABYTES 32768
#define BUFSZ  49152
#define LDS_TOTAL 98304

typedef __bf16 bf16;
typedef __attribute__((ext_vector_type(8))) __bf16 bf16x8;
typedef __attribute__((ext_vector_type(4))) float f32x4;

__device__ __forceinline__ void gload_lds16(const bf16* g, void* l) {
    __builtin_amdgcn_global_load_lds(
        (const __attribute__((address_space(1))) void*)g,
        (__attribute__((address_space(3))) void*)l, 16, 0, 0);
}

// ---------------- transpose + prep (fused launch, z selects role) ----------------
__global__ __launch_bounds__(256) void transpose_prep(const float* __restrict__ magn,
                                                      const float* __restrict__ phase,
                                                      const float* __restrict__ rk,
                                                      const float* __restrict__ ik,
                                                      bf16* __restrict__ Xt,
                                                      bf16* __restrict__ Kc) {
    const int tid = threadIdx.x;
    const int src = blockIdx.z;

    if (src == 2) {                      // prep: 512*1024 elems, guard the tail
        int idx = (blockIdx.y * 512 + blockIdx.x) * 256 + tid;
        if (idx >= 512 * KDIM) return;
        int cp = idx >> 10;              // c' = 0..511, actual row = 512+c'
        int k = idx & 1023;
        int row = 512 + cp;
        float v = (k < NFREQ) ? rk[row * NFREQ + k] : ik[row * NFREQ + (k - NFREQ)];
        Kc[idx] = (bf16)(v * (1.0f / 1024.0f));
        return;
    }

    __shared__ bf16 tile[64][68];
    const int tt  = blockIdx.x & 63;
    const int ft  = blockIdx.x >> 6;
    const int b   = blockIdx.y;
    const float* in = src ? phase : magn;
    const int f0 = ft * 64, t0 = tt * 64;
    const size_t base = (size_t)b * NFREQ * TDIM;

    const int r0 = tid >> 4;
    const int c4 = (tid & 15) * 4;
#pragma unroll
    for (int i = 0; i < 4; i++) {
        int r = r0 + i * 16;
        const float4 v = *(const float4*)&in[base + (size_t)(f0 + r) * TDIM + t0 + c4];
        tile[r][c4 + 0] = (bf16)v.x;
        tile[r][c4 + 1] = (bf16)v.y;
        tile[r][c4 + 2] = (bf16)v.z;
        tile[r][c4 + 3] = (bf16)v.w;
    }
    __syncthreads();
    const int kbase = src * NFREQ + f0;
#pragma unroll
    for (int i = 0; i < 2; i++) {
        int ch = tid + 256 * i;
        int tr = ch >> 3;
        int c8 = (ch & 7) * 8;
        bf16x8 o;
#pragma unroll
        for (int j = 0; j < 8; j++) o[j] = tile[c8 + j][tr];
        *(bf16x8*)&Xt[((size_t)b * TDIM + t0 + tr) * KDIM + kbase + c8] = o;
    }
}

// ---------------- GEMM with DFT symmetry, 2-phase K-tiles ----------------
// U[c'] = K-tiles 0..7 (RK vs m), V[c'] = K-tiles 8..15 (IK vs p).
// out[512+mrow] = U - V ; out[512-mrow] = U + V ; row 0 via x>=64 blocks.
// 2 phases/tile (q = M-half, 16 MFMA each) — R13: halves barrier count vs R12.
// vmcnt ledger: q0 issues {A3,B0,B1}(v+1); q1 issues {A0..A2}(v+2); q1-end
// vmcnt(3) leaves exactly A0..A2(v+2) in flight (R4 counting invariant).
// One tile per WG (persistence BANNED, R3/R9). gid%8 = x%8 -> bm-sharers of a
// (b,bn) panel share an XCD (80%8==0).
__global__ __launch_bounds__(512, 2) void gemm8(const bf16* __restrict__ Kc,
                                                const bf16* __restrict__ Xt,
                                                float* __restrict__ out) {
    extern __shared__ __align__(16) char smem[];

    const int tid = threadIdx.x;
    const int w = tid >> 6;          // wave 0..7
    const int l = tid & 63;
    const int x = blockIdx.x;
    const int b = blockIdx.y;

    // ---- row-0 duty blocks: out[b][0][t] = sum_k w_k * Xt[b][t][k<512] / 1024
    if (x >= 64) {
        const int bn0 = x - 64;              // 0..15, t-range bn0*256
        for (int i = 0; i < 32; ++i) {
            const int t = bn0 * 256 + w * 32 + i;
            const bf16x8 v = *(const bf16x8*)&Xt[((size_t)b * TDIM + t) * KDIM + l * 8];
            float s = 0.f;
#pragma unroll
            for (int j = 0; j < 8; j++) s += (float)v[j];
            if (l == 63) s -= 0.5f * (float)v[7];    // freq 512 weight 1 (not 2)
            s *= 2.0f;
#pragma unroll
            for (int m_ = 32; m_ >= 1; m_ >>= 1) s += __shfl_xor(s, m_);
            if (l == 0) out[(size_t)b * CDIM * TDIM + t] = s * (1.0f / 1024.0f);
        }
        return;
    }

    const int bm = x >> 5;           // 0..1  (c' tiles of 256)
    const int bn = x & 31;           // 0..31 (t tiles of 128)

    const bf16* Ab    = Kc + (size_t)(bm * 256) * KDIM;
    const bf16* Bbase = Xt + ((size_t)b * TDIM + bn * 128) * KDIM;

    // staging geometry (R4-verified pattern; B mirrors it at 64 rows/step)
    const int srow  = ((w >> 2) * 128) + ((w & 3) * 8);
    const int srowB = ((w >> 2) * 64) + ((w & 3) * 8);
    const int ssub  = l >> 3;
    const int scol  = ((l & 7) ^ ssub) * 8;

    // fragment-read geometry
    const int wr = w >> 2;           // 0..1 (M half)
    const int wc = w & 3;            // 0..3 (N quarter of 128 -> 32 each)
    const int fr = l & 15;
    const int l16 = l >> 4;
    const int fx = fr & 7;

    f32x4 accU[8][2] = {};
    f32x4 accV[8][2] = {};

#define STAGE_A(curb, q, kt) \
    gload_lds16(Ab + (size_t)(srow + (q)*32 + ssub) * KDIM + (kt)*64 + scol, \
                smem + (curb)*BUFSZ + (srow + (q)*32) * 128)
#define STAGE_B(curb, q, kt) \
    gload_lds16(Bbase + (size_t)(srowB + (q)*32 + ssub) * KDIM + (kt)*64 + scol, \
                smem + (curb)*BUFSZ + ABYTES + (srowB + (q)*32) * 128)

    // prologue: tile0 A(4)+B(2) into buf0; tile1 A q0..2 into buf1; keep 3
#pragma unroll
    for (int q = 0; q < 4; q++) STAGE_A(0, q, 0);
    STAGE_B(0, 0, 0); STAGE_B(0, 1, 0);
    STAGE_A(1, 0, 1); STAGE_A(1, 1, 1); STAGE_A(1, 2, 1);
    asm volatile("s_waitcnt vmcnt(3)" ::: "memory");
    __builtin_amdgcn_s_barrier();
    __builtin_amdgcn_sched_barrier(0);

    // per-tile body: 2 phases, 16 MFMA each; ACC selects U or V
#define GTILE(ACC, v)                                                          \
    {                                                                          \
        const int cur = (v) & 1;                                               \
        const char* At = smem + cur * BUFSZ;                                   \
        const char* Bt = At + ABYTES;                                          \
        bf16x8 bfr[2][2];                                                      \
        _Pragma("unroll")                                                      \
        for (int q = 0; q < 2; q++) {                                          \
            bf16x8 afr[4][2];                                                  \
            _Pragma("unroll")                                                  \
            for (int mi = 0; mi < 4; mi++)                                     \
                _Pragma("unroll")                                              \
                for (int kk = 0; kk < 2; kk++) {                               \
                    const int r = wr * 128 + (q * 4 + mi) * 16 + fr;           \
                    afr[mi][kk] = *(const bf16x8*)(At + r * 128                \
                                   + (((kk * 4 + l16) ^ fx) * 16));            \
                }                                                              \
            if (q == 0) {                                                      \
                _Pragma("unroll")                                              \
                for (int n = 0; n < 2; n++)                                    \
                    _Pragma("unroll")                                          \
                    for (int kk = 0; kk < 2; kk++) {                           \
                        const int r = wc * 32 + n * 16 + fr;                   \
                        bfr[n][kk] = *(const bf16x8*)(Bt + r * 128             \
                                      + (((kk * 4 + l16) ^ fx) * 16));         \
                    }                                                          \
                if ((v) + 1 < NT) {                                            \
                    const int nc = cur ^ 1;                                    \
                    STAGE_A(nc, 3, (v) + 1);                                   \
                    STAGE_B(nc, 0, (v) + 1); STAGE_B(nc, 1, (v) + 1);          \
                }                                                              \
            } else {                                                           \
                if ((v) + 2 < NT) {                                            \
                    STAGE_A(cur, 0, (v) + 2); STAGE_A(cur, 1, (v) + 2);        \
                    STAGE_A(cur, 2, (v) + 2);                                  \
                }                                                              \
            }                                                                  \
            __builtin_amdgcn_s_barrier();                                      \
            __builtin_amdgcn_s_setprio(1);                                     \
            _Pragma("unroll")                                                  \
            for (int mi = 0; mi < 4; mi++)                                     \
                _Pragma("unroll")                                              \
                for (int n = 0; n < 2; n++)                                    \
                    _Pragma("unroll")                                          \
                    for (int kk = 0; kk < 2; kk++)                             \
                        ACC[q * 4 + mi][n] = __builtin_amdgcn_mfma_f32_16x16x32_bf16( \
                            afr[mi][kk], bfr[n][kk], ACC[q * 4 + mi][n], 0, 0, 0);    \
            __builtin_amdgcn_s_setprio(0);                                     \
            if (q == 1) {                                                      \
                if ((v) < NT - 2) { asm volatile("s_waitcnt vmcnt(3)" ::: "memory"); } \
                else              { asm volatile("s_waitcnt vmcnt(0)" ::: "memory"); } \
            }                                                                  \
            __builtin_amdgcn_s_barrier();                                      \
            __builtin_amdgcn_sched_barrier(0);                                 \
        }                                                                      \
    }

    for (int v = 0; v < 8; ++v)  GTILE(accU, v)      // U: RK vs m (k 0..511)
    for (int v = 8; v < 15; ++v) GTILE(accV, v)      // V: IK vs p (k 512..959)

    // -------- peeled final tile (v=15, buf1, accV): barrier-free, fused C-write
    {
        const char* At = smem + BUFSZ;
        const char* Bt = At + ABYTES;
        const int cr = l16 * 4;
        const int cc = fr;
        const size_t obatch = (size_t)b * CDIM * TDIM;
        const int colbase = bn * 128 + wc * 32;
        bf16x8 bfr[2][2];

#pragma unroll
        for (int q = 0; q < 2; q++) {
            bf16x8 afr[4][2];
#pragma unroll
            for (int mi = 0; mi < 4; mi++)
#pragma unroll
                for (int kk = 0; kk < 2; kk++) {
                    const int r = wr * 128 + (q * 4 + mi) * 16 + fr;
                    afr[mi][kk] = *(const bf16x8*)(At + r * 128 + (((kk * 4 + l16) ^ fx) * 16));
                }
            if (q == 0) {
#pragma unroll
                for (int n = 0; n < 2; n++)
#pragma unroll
                    for (int kk = 0; kk < 2; kk++) {
                        const int r = wc * 32 + n * 16 + fr;
                        bfr[n][kk] = *(const bf16x8*)(Bt + r * 128 + (((kk * 4 + l16) ^ fx) * 16));
                    }
            }

            __builtin_amdgcn_s_setprio(1);
#pragma unroll
            for (int mi = 0; mi < 4; mi++)
#pragma unroll
                for (int n = 0; n < 2; n++)
#pragma unroll
                    for (int kk = 0; kk < 2; kk++)
                        accV[q * 4 + mi][n] = __builtin_amdgcn_mfma_f32_16x16x32_bf16(
                            afr[mi][kk], bfr[n][kk], accV[q * 4 + mi][n], 0, 0, 0);
            __builtin_amdgcn_s_setprio(0);

            // quarters m = 4q .. 4q+3 now final -> paired stores drain under q+1
#pragma unroll
            for (int mi = 0; mi < 4; mi++) {
                const int m = q * 4 + mi;
#pragma unroll
                for (int n = 0; n < 2; n++)
#pragma unroll
                    for (int j = 0; j < 4; j++) {
                        const int mrow = bm * 256 + wr * 128 + m * 16 + cr + j;
                        const float u = accU[m][n][j];
                        const float vv = accV[m][n][j];
                        const int col = colbase + n * 16 + cc;
                        if (mrow > 0)
                            out[obatch + (size_t)(512 - mrow) * TDIM + col] = u + vv;
                        out[obatch + (size_t)(512 + mrow) * TDIM + col] = u - vv;
                    }
            }
        }
    }
#undef GTILE
#undef STAGE_A
#undef STAGE_B
}

// ---------------- fallback (ws too small): naive f32 ----------------
__global__ __launch_bounds__(256) void naive_kernel(const float* __restrict__ m,
                                                    const float* __restrict__ p,
                                                    const float* __restrict__ rk,
                                                    const float* __restrict__ ik,
                                                    float* __restrict__ out) {
    size_t idx = (size_t)blockIdx.x * 256 + threadIdx.x;
    int t = idx & 4095;
    size_t r = idx >> 12;
    int c = (int)(r & 1023);
    int b = (int)(r >> 10);
    float acc = 0.f;
    for (int f = 0; f < NFREQ; f++) {
        acc += rk[c * NFREQ + f] * m[((size_t)b * NFREQ + f) * TDIM + t]
             - ik[c * NFREQ + f] * p[((size_t)b * NFREQ + f) * TDIM + t];
    }
    out[idx] = acc * (1.0f / 1024.0f);
}

extern "C" void kernel_launch(void* const* d_in, const int* in_sizes, int n_in,
                              void* d_out, int out_size, void* d_ws, size_t ws_size,
                              hipStream_t stream) {
    const float* magn  = (const float*)d_in[0];
    const float* phase = (const float*)d_in[1];
    const float* rk    = (const float*)d_in[2];
    const float* ik    = (const float*)d_in[3];
    float* out = (float*)d_out;

    const size_t kc_bytes = (size_t)512 * KDIM * sizeof(bf16);           // 1 MB
    const size_t xt_bytes = (size_t)BATCH * TDIM * KDIM * sizeof(bf16);  // 64 MB
    if (ws_size < kc_bytes + xt_bytes) {
        naive_kernel<<<(CDIM * TDIM * BATCH) / 256, 256, 0, stream>>>(magn, phase, rk, ik, out);
        return;
    }

    bf16* Kc = (bf16*)d_ws;
    bf16* Xt = (bf16*)((char*)d_ws + kc_bytes);

    (void)hipFuncSetAttribute((const void*)gemm8,
                              hipFuncAttributeMaxDynamicSharedMemorySize, LDS_TOTAL);

    transpose_prep<<<dim3(512, BATCH, 3), 256, 0, stream>>>(magn, phase, rk, ik, Xt, Kc);
    gemm8<<<dim3(80, BATCH), 512, LDS_TOTAL, stream>>>(Kc, Xt, out);
}